// Round 6
// baseline (1062.890 us; speedup 1.0000x reference)
//
#include <hip/hip_runtime.h>

#define NPTS 131072
#define DIM 256
#define NK 128
#define NITER 10
#define SEG 16

typedef _Float16 half8 __attribute__((ext_vector_type(8)));
typedef _Float16 half4v __attribute__((ext_vector_type(4)));
typedef float f32x4 __attribute__((ext_vector_type(4)));

#define RSCALE 4096.0f
#define RINV 2.44140625e-4f  // 2^-12 exact

// ---------------------------------------------------------------------------
// x2[i] = sum_d x[i][d]^2   (16 threads per point)
// ---------------------------------------------------------------------------
__global__ void x2_kernel(const float* __restrict__ x, float* __restrict__ x2) {
  int tid = threadIdx.x;
  int p = blockIdx.x * 16 + (tid >> 4);
  int part = tid & 15;
  const float4* xr = (const float4*)(x + (size_t)p * DIM);
  float s = 0.f;
#pragma unroll
  for (int j = 0; j < 4; ++j) {
    float4 v = xr[part * 4 + j];
    s += v.x * v.x;
    s += v.y * v.y;
    s += v.z * v.z;
    s += v.w * v.w;
  }
#pragma unroll
  for (int m = 8; m >= 1; m >>= 1) s += __shfl_xor(s, m, 16);
  if (part == 0) x2[p] = s;
}

// ---------------------------------------------------------------------------
// c2[k] = sum_d c[k][d]^2   (one wave per cluster, init only)
// ---------------------------------------------------------------------------
__global__ void c2_kernel(const float* __restrict__ c, float* __restrict__ c2) {
  int k = blockIdx.x, lane = threadIdx.x;
  float4 v = ((const float4*)(c + (size_t)k * DIM))[lane];
  float s = v.x * v.x + v.y * v.y + v.z * v.z + v.w * v.w;
#pragma unroll
  for (int m = 32; m >= 1; m >>= 1) s += __shfl_xor(s, m, 64);
  if (lane == 0) c2[k] = s;
}

// ---------------------------------------------------------------------------
// fp32 -> (f16 hi, f16 scaled residual). a = hi + lo * 2^-12 + O(2^-22 a)
// ---------------------------------------------------------------------------
__global__ void convert_x_kernel(const float* __restrict__ x, _Float16* __restrict__ x1,
                                 _Float16* __restrict__ x2s) {
  int i = blockIdx.x * 256 + threadIdx.x;  // float4 index
  float4 v = ((const float4*)x)[i];
  float f[4] = {v.x, v.y, v.z, v.w};
  half4v h, l;
#pragma unroll
  for (int j = 0; j < 4; ++j) {
    _Float16 hi = (_Float16)f[j];
    float r = f[j] - (float)hi;
    h[j] = hi;
    l[j] = (_Float16)(r * RSCALE);
  }
  ((half4v*)x1)[i] = h;
  ((half4v*)x2s)[i] = l;
}

// ---------------------------------------------------------------------------
// centroids fp32 -> chunk-tiled f16 split layout for LDS staging:
// ct[chunk][0][k][d32] = hi, ct[chunk][1][k][d32] = lo  (chunk = 32 dims)
// ---------------------------------------------------------------------------
__global__ void convert_c_kernel(const float* __restrict__ c, _Float16* __restrict__ ct) {
  int i = blockIdx.x * 256 + threadIdx.x;  // float4 index, 8192 total
  int k = i >> 6;
  int d4 = i & 63;
  float4 v = ((const float4*)c)[i];
  float f[4] = {v.x, v.y, v.z, v.w};
  half4v h, l;
#pragma unroll
  for (int j = 0; j < 4; ++j) {
    _Float16 hi = (_Float16)f[j];
    float r = f[j] - (float)hi;
    h[j] = hi;
    l[j] = (_Float16)(r * RSCALE);
  }
  int ch = d4 >> 3;
  int idx4 = ch * 2048 + k * 8 + (d4 & 7);
  ((half4v*)ct)[idx4] = h;
  ((half4v*)ct)[idx4 + 1024] = l;
}

// ---------------------------------------------------------------------------
// MFMA assignment: 256 threads = 4 waves x 32 points = 128 points/block.
// Centroid chunk (32 dims, hi+lo = 16 KB) double-buffered in LDS.
// ---------------------------------------------------------------------------
__global__ __launch_bounds__(256, 2) void assign_mfma_kernel(
    const _Float16* __restrict__ x1, const _Float16* __restrict__ x2s,
    const _Float16* __restrict__ ct, const float* __restrict__ x2,
    const float* __restrict__ c2, int* __restrict__ out) {
  __shared__ __align__(16) _Float16 cbuf[2][8192];

  int tid = threadIdx.x;
  int lane = tid & 63;
  int w = tid >> 6;
  int lcol = lane & 15;
  int lgrp = lane >> 4;
  int row0 = blockIdx.x * 128 + w * 32;

  const _Float16* xa = x1 + (size_t)(row0 + lcol) * DIM + lgrp * 8;
  const _Float16* xb = x2s + (size_t)(row0 + lcol) * DIM + lgrp * 8;
  const half8* ctv = (const half8*)ct;

  f32x4 acc1[2][8], acc2[2][8];
#pragma unroll
  for (int rt = 0; rt < 2; ++rt)
#pragma unroll
    for (int c8 = 0; c8 < 8; ++c8) {
      acc1[rt][c8] = f32x4{0.f, 0.f, 0.f, 0.f};
      acc2[rt][c8] = f32x4{0.f, 0.f, 0.f, 0.f};
    }

  half8 A1[2], A2[2], nA1[2], nA2[2], sreg[4];

#pragma unroll
  for (int r = 0; r < 4; ++r) sreg[r] = ctv[r * 256 + tid];
#pragma unroll
  for (int rt = 0; rt < 2; ++rt) {
    A1[rt] = *(const half8*)(xa + rt * 16 * DIM);
    A2[rt] = *(const half8*)(xb + rt * 16 * DIM);
  }
#pragma unroll
  for (int r = 0; r < 4; ++r) ((half8*)cbuf[0])[r * 256 + tid] = sreg[r];
  __syncthreads();

#pragma unroll
  for (int ck = 0; ck < 8; ++ck) {
    const int cb = ck & 1;
    if (ck < 7) {
#pragma unroll
      for (int r = 0; r < 4; ++r) sreg[r] = ctv[(ck + 1) * 1024 + r * 256 + tid];
#pragma unroll
      for (int rt = 0; rt < 2; ++rt) {
        nA1[rt] = *(const half8*)(xa + rt * 16 * DIM + (ck + 1) * 32);
        nA2[rt] = *(const half8*)(xb + rt * 16 * DIM + (ck + 1) * 32);
      }
    }
#pragma unroll
    for (int c8 = 0; c8 < 8; ++c8) {
      int bidx = (c8 * 16 + lcol) * 32 + lgrp * 8;
      half8 b1 = *(const half8*)&cbuf[cb][bidx];
      half8 b2 = *(const half8*)&cbuf[cb][4096 + bidx];
#pragma unroll
      for (int rt = 0; rt < 2; ++rt) {
        acc1[rt][c8] = __builtin_amdgcn_mfma_f32_16x16x32_f16(A1[rt], b1, acc1[rt][c8], 0, 0, 0);
        acc2[rt][c8] = __builtin_amdgcn_mfma_f32_16x16x32_f16(A1[rt], b2, acc2[rt][c8], 0, 0, 0);
        acc2[rt][c8] = __builtin_amdgcn_mfma_f32_16x16x32_f16(A2[rt], b1, acc2[rt][c8], 0, 0, 0);
      }
    }
    if (ck < 7) {
#pragma unroll
      for (int r = 0; r < 4; ++r) ((half8*)cbuf[cb ^ 1])[r * 256 + tid] = sreg[r];
#pragma unroll
      for (int rt = 0; rt < 2; ++rt) {
        A1[rt] = nA1[rt];
        A2[rt] = nA2[rt];
      }
      __syncthreads();
    }
  }

#pragma unroll
  for (int rt = 0; rt < 2; ++rt) {
    int pbase = row0 + rt * 16 + lgrp * 4;
    float x2p[4];
#pragma unroll
    for (int r = 0; r < 4; ++r) x2p[r] = x2[pbase + r];
    float bv[4];
    int bk[4];
#pragma unroll
    for (int r = 0; r < 4; ++r) { bv[r] = 3.4e38f; bk[r] = 0; }
#pragma unroll
    for (int c8 = 0; c8 < 8; ++c8) {
      int kc = c8 * 16 + lcol;
      float c2k = c2[kc];
#pragma unroll
      for (int r = 0; r < 4; ++r) {
        float dot = fmaf(acc2[rt][c8][r], RINV, acc1[rt][c8][r]);
        float d = fmaf(-2.f, dot, x2p[r]) + c2k;
        if (d < bv[r]) { bv[r] = d; bk[r] = kc; }
      }
    }
#pragma unroll
    for (int m = 1; m <= 8; m <<= 1) {
#pragma unroll
      for (int r = 0; r < 4; ++r) {
        float ov = __shfl_xor(bv[r], m, 64);
        int ok = __shfl_xor(bk[r], m, 64);
        if (ov < bv[r] || (ov == bv[r] && ok < bk[r])) { bv[r] = ov; bk[r] = ok; }
      }
    }
    if (lcol == 0) {
#pragma unroll
      for (int r = 0; r < 4; ++r) out[pbase + r] = bk[r];
    }
  }
}

// ---------------------------------------------------------------------------
// fp32 fallback assignment (R2-proven) used when ws is too small
// ---------------------------------------------------------------------------
__global__ void assign_kernel(const float* __restrict__ x, const float* __restrict__ c,
                              const float* __restrict__ x2, const float* __restrict__ c2,
                              int* __restrict__ assign_out) {
  __shared__ float4 xs4[64 * 4];
  __shared__ float4 cs4[128 * 4];
  __shared__ float redv[64][17];
  __shared__ int redk[64][17];

  int tid = threadIdx.x;
  int tx = tid & 15;
  int ty = tid >> 4;
  int row0 = blockIdx.x * 64;

  float acc[4][8];
#pragma unroll
  for (int a = 0; a < 4; ++a)
#pragma unroll
    for (int b = 0; b < 8; ++b) acc[a][b] = 0.f;

  for (int ck = 0; ck < 16; ++ck) {
    {
      int p = tid >> 2, d4 = tid & 3;
      float4 v = *(const float4*)(x + (size_t)(row0 + p) * DIM + ck * 16 + d4 * 4);
      xs4[p * 4 + (d4 ^ ((p >> 2) & 3))] = v;
    }
#pragma unroll
    for (int r = 0; r < 2; ++r) {
      int idx = tid + r * 256;
      int kk = idx >> 2, dd = idx & 3;
      float4 v = *(const float4*)(c + (size_t)kk * DIM + ck * 16 + dd * 4);
      cs4[kk * 4 + (dd ^ ((kk >> 3) & 3))] = v;
    }
    __syncthreads();
#pragma unroll
    for (int d4 = 0; d4 < 4; ++d4) {
      float4 xr[4], cr[8];
#pragma unroll
      for (int pp = 0; pp < 4; ++pp) xr[pp] = xs4[(tx * 4 + pp) * 4 + (d4 ^ (tx & 3))];
#pragma unroll
      for (int kk = 0; kk < 8; ++kk) cr[kk] = cs4[(ty * 8 + kk) * 4 + (d4 ^ (ty & 3))];
#pragma unroll
      for (int pp = 0; pp < 4; ++pp)
#pragma unroll
        for (int kk = 0; kk < 8; ++kk) {
          acc[pp][kk] = fmaf(xr[pp].x, cr[kk].x, acc[pp][kk]);
          acc[pp][kk] = fmaf(xr[pp].y, cr[kk].y, acc[pp][kk]);
          acc[pp][kk] = fmaf(xr[pp].z, cr[kk].z, acc[pp][kk]);
          acc[pp][kk] = fmaf(xr[pp].w, cr[kk].w, acc[pp][kk]);
        }
    }
    __syncthreads();
  }

  float x2p[4];
#pragma unroll
  for (int pp = 0; pp < 4; ++pp) x2p[pp] = x2[row0 + tx * 4 + pp];

  float bestv[4];
  int bestk[4];
#pragma unroll
  for (int pp = 0; pp < 4; ++pp) { bestv[pp] = 3.4e38f; bestk[pp] = 0; }
#pragma unroll
  for (int kk = 0; kk < 8; ++kk) {
    float c2k = c2[ty * 8 + kk];
#pragma unroll
    for (int pp = 0; pp < 4; ++pp) {
      float d = fmaf(-2.f, acc[pp][kk], x2p[pp]) + c2k;
      if (d < bestv[pp]) { bestv[pp] = d; bestk[pp] = ty * 8 + kk; }
    }
  }
#pragma unroll
  for (int pp = 0; pp < 4; ++pp) {
    redv[tx * 4 + pp][ty] = bestv[pp];
    redk[tx * 4 + pp][ty] = bestk[pp];
  }
  __syncthreads();
  if (tid < 64) {
    float bv = redv[tid][0];
    int bk = redk[tid][0];
#pragma unroll
    for (int t = 1; t < 16; ++t) {
      float v = redv[tid][t];
      if (v < bv) { bv = v; bk = redk[tid][t]; }
    }
    assign_out[row0 + tid] = bk;
  }
}

// ---------------------------------------------------------------------------
__global__ void hist_kernel(const int* __restrict__ assign_in, int* __restrict__ hist) {
  __shared__ int h[NK];
  int tid = threadIdx.x, b = blockIdx.x;
  if (tid < NK) h[tid] = 0;
  __syncthreads();
#pragma unroll
  for (int r = 0; r < 4; ++r) {
    int a = assign_in[b * 1024 + r * 256 + tid];
    atomicAdd(&h[a], 1);
  }
  __syncthreads();
  if (tid < NK) hist[b * NK + tid] = h[tid];
}

__global__ void scan_kernel(const int* __restrict__ hist, int* __restrict__ base,
                            int* __restrict__ counts, int* __restrict__ cbase) {
  __shared__ int h[128 * NK];
  int tid = threadIdx.x;
  for (int i = tid; i < 128 * NK; i += 256) h[i] = hist[i];
  __syncthreads();
  if (tid < NK) {
    int run = 0;
    for (int b = 0; b < 128; ++b) {
      int v = h[b * NK + tid];
      h[b * NK + tid] = run;
      run += v;
    }
    counts[tid] = run;
  }
  __syncthreads();
  if (tid == 0) {
    int cb = 0;
#pragma unroll 4
    for (int j = 0; j < NK; ++j) {
      cbase[j] = cb;
      cb += counts[j];
    }
  }
  __syncthreads();
  if (tid < NK) {
    int cbk = cbase[tid];
    for (int b = 0; b < 128; ++b) base[b * NK + tid] = h[b * NK + tid] + cbk;
  }
}

__global__ void scatter_kernel(const int* __restrict__ assign_in, const int* __restrict__ base,
                               int* __restrict__ perm) {
  __shared__ int cnt[NK];
  int lane = threadIdx.x, b = blockIdx.x;
  cnt[lane] = base[b * NK + lane];
  cnt[lane + 64] = base[b * NK + lane + 64];
  __syncthreads();
  for (int r = 0; r < 16; ++r) {
    int p = b * 1024 + r * 64 + lane;
    int a = assign_in[p];
    unsigned long long mask = ~0ull;
#pragma unroll
    for (int j = 0; j < 7; ++j) {
      unsigned long long bal = __ballot((a >> j) & 1);
      mask &= ((a >> j) & 1) ? bal : ~bal;
    }
    int rank = __popcll(mask & ((1ull << lane) - 1ull));
    int pos = cnt[a] + rank;
    perm[pos] = p;
    __syncthreads();
    if (rank == 0) cnt[a] += (int)__popcll(mask);
    __syncthreads();
  }
}

// ---------------------------------------------------------------------------
// seg_sum v2: fp32 x, 4 x 64-lane groups per block. Each group sums a
// CONTIGUOUS quarter of segment (k,s); lane owns float4 of dims (1 KB/row
// per wave-instruction). Group partials added in fixed order (deterministic).
// ---------------------------------------------------------------------------
__global__ __launch_bounds__(256) void seg_sum_v2_kernel(
    const float* __restrict__ x, const int* __restrict__ perm,
    const int* __restrict__ counts, const int* __restrict__ cbase,
    float* __restrict__ partial) {
  __shared__ float4 red[4][64];
  int tid = threadIdx.x;
  int tg = tid >> 6;    // group 0..3
  int lane = tid & 63;  // float4 index within row
  int k = blockIdx.x, s = blockIdx.y;
  int cnt = counts[k], off = cbase[k];
  int j0 = (int)(((long long)cnt * s) / SEG);
  int j1 = (int)(((long long)cnt * (s + 1)) / SEG);
  int len = j1 - j0;
  int jj0 = j0 + (int)(((long long)len * tg) / 4);
  int jj1 = j0 + (int)(((long long)len * (tg + 1)) / 4);

  float4 acc = {0.f, 0.f, 0.f, 0.f};
  int j = jj0;
  for (; j + 2 <= jj1; j += 2) {
    int p0 = perm[off + j];
    int p1 = perm[off + j + 1];
    float4 v0 = ((const float4*)(x + (size_t)p0 * DIM))[lane];
    float4 v1 = ((const float4*)(x + (size_t)p1 * DIM))[lane];
    acc.x += v0.x; acc.y += v0.y; acc.z += v0.z; acc.w += v0.w;
    acc.x += v1.x; acc.y += v1.y; acc.z += v1.z; acc.w += v1.w;
  }
  for (; j < jj1; ++j) {
    int p = perm[off + j];
    float4 v = ((const float4*)(x + (size_t)p * DIM))[lane];
    acc.x += v.x; acc.y += v.y; acc.z += v.z; acc.w += v.w;
  }
  red[tg][lane] = acc;
  __syncthreads();
  if (tg == 0) {
    float4 s0 = red[0][lane], s1 = red[1][lane], s2 = red[2][lane], s3 = red[3][lane];
    float4 t;
    t.x = ((s0.x + s1.x) + s2.x) + s3.x;
    t.y = ((s0.y + s1.y) + s2.y) + s3.y;
    t.z = ((s0.z + s1.z) + s2.z) + s3.z;
    t.w = ((s0.w + s1.w) + s2.w) + s3.w;
    ((float4*)(partial + ((size_t)k * SEG + s) * DIM))[lane] = t;
  }
}

__global__ void seg_sum_kernel(const float* __restrict__ x, const int* __restrict__ perm,
                               const int* __restrict__ counts, const int* __restrict__ cbase,
                               float* __restrict__ partial) {
  int k = blockIdx.x, s = blockIdx.y, d = threadIdx.x;
  int cnt = counts[k], off = cbase[k];
  int j0 = (int)(((long long)cnt * s) / SEG);
  int j1 = (int)(((long long)cnt * (s + 1)) / SEG);
  float sum = 0.f;
  int j = j0;
  for (; j + 4 <= j1; j += 4) {
    int p0 = perm[off + j + 0];
    int p1 = perm[off + j + 1];
    int p2 = perm[off + j + 2];
    int p3 = perm[off + j + 3];
    sum += x[(size_t)p0 * DIM + d];
    sum += x[(size_t)p1 * DIM + d];
    sum += x[(size_t)p2 * DIM + d];
    sum += x[(size_t)p3 * DIM + d];
  }
  for (; j < j1; ++j) sum += x[(size_t)perm[off + j] * DIM + d];
  partial[((size_t)k * SEG + s) * DIM + d] = sum;
}

__global__ void reduce_kernel(const float* __restrict__ partial, const int* __restrict__ counts,
                              float* __restrict__ c, float* __restrict__ c2) {
  __shared__ float wsum[4];
  int k = blockIdx.x, d = threadIdx.x;
  int cnt = counts[k];
  float s = 0.f;
#pragma unroll
  for (int t = 0; t < SEG; ++t) s += partial[((size_t)k * SEG + t) * DIM + d];

  float nc;
  if (cnt > 0)
    nc = s / fmaxf((float)cnt, 1.0f);
  else
    nc = c[(size_t)k * DIM + d];
  c[(size_t)k * DIM + d] = nc;

  float s2 = nc * nc;
#pragma unroll
  for (int m = 32; m >= 1; m >>= 1) s2 += __shfl_xor(s2, m, 64);
  if ((threadIdx.x & 63) == 0) wsum[threadIdx.x >> 6] = s2;
  __syncthreads();
  if (threadIdx.x == 0) c2[k] = wsum[0] + wsum[1] + wsum[2] + wsum[3];
}

// ---------------------------------------------------------------------------
extern "C" void kernel_launch(void* const* d_in, const int* in_sizes, int n_in,
                              void* d_out, int out_size, void* d_ws, size_t ws_size,
                              hipStream_t stream) {
  const float* x = (const float*)d_in[0];
  char* ws = (char*)d_ws;

  const size_t NEED_BIG = 138282496;  // ~138.3 MB
  bool use_mfma = ws_size >= NEED_BIG;

  if (use_mfma) {
    _Float16* x1 = (_Float16*)(ws + 0);           // 64 MB
    _Float16* x2s = (_Float16*)(ws + 67108864);   // 64 MB
    float* c = (float*)(ws + 134217728);          // 128 KB (fp32 centroids)
    _Float16* ct = (_Float16*)(ws + 134348800);   // 128 KB (chunk-tiled split)
    float* c2 = (float*)(ws + 134479872);         // 512 B
    float* x2 = (float*)(ws + 134480384);         // 512 KB
    int* assignb = (int*)(ws + 135004672);        // 512 KB
    int* hist = (int*)(ws + 135528960);           // 64 KB
    int* base = (int*)(ws + 135594496);           // 64 KB
    int* counts = (int*)(ws + 135660032);         // 512 B
    int* cbase = (int*)(ws + 135660544);          // 512 B
    int* perm = (int*)(ws + 135661056);           // 512 KB
    float* partial = (float*)(ws + 136185344);    // 2 MB

    hipMemcpyAsync(c, x, (size_t)NK * DIM * sizeof(float), hipMemcpyDeviceToDevice, stream);
    convert_x_kernel<<<NPTS * DIM / 4 / 256, 256, 0, stream>>>(x, x1, x2s);
    x2_kernel<<<NPTS / 16, 256, 0, stream>>>(x, x2);
    c2_kernel<<<NK, 64, 0, stream>>>(c, c2);
    convert_c_kernel<<<NK * DIM / 4 / 256, 256, 0, stream>>>(c, ct);

    for (int it = 0; it < NITER; ++it) {
      assign_mfma_kernel<<<NPTS / 128, 256, 0, stream>>>(x1, x2s, ct, x2, c2, assignb);
      hist_kernel<<<NPTS / 1024, 256, 0, stream>>>(assignb, hist);
      scan_kernel<<<1, 256, 0, stream>>>(hist, base, counts, cbase);
      scatter_kernel<<<NPTS / 1024, 64, 0, stream>>>(assignb, base, perm);
      seg_sum_v2_kernel<<<dim3(NK, SEG), 256, 0, stream>>>(x, perm, counts, cbase, partial);
      reduce_kernel<<<NK, 256, 0, stream>>>(partial, counts, c, c2);
      convert_c_kernel<<<NK * DIM / 4 / 256, 256, 0, stream>>>(c, ct);
    }
    assign_mfma_kernel<<<NPTS / 128, 256, 0, stream>>>(x1, x2s, ct, x2, c2, (int*)d_out);
  } else {
    float* c = (float*)(ws + 0);
    float* c2 = (float*)(ws + 131072);
    float* x2 = (float*)(ws + 132096);
    int* assignb = (int*)(ws + 656384);
    int* hist = (int*)(ws + 1180672);
    int* base = (int*)(ws + 1246208);
    int* counts = (int*)(ws + 1311744);
    int* cbase = (int*)(ws + 1312256);
    int* perm = (int*)(ws + 1312768);
    float* partial = (float*)(ws + 1837056);

    hipMemcpyAsync(c, x, (size_t)NK * DIM * sizeof(float), hipMemcpyDeviceToDevice, stream);
    x2_kernel<<<NPTS / 16, 256, 0, stream>>>(x, x2);
    c2_kernel<<<NK, 64, 0, stream>>>(c, c2);

    for (int it = 0; it < NITER; ++it) {
      assign_kernel<<<NPTS / 64, 256, 0, stream>>>(x, c, x2, c2, assignb);
      hist_kernel<<<NPTS / 1024, 256, 0, stream>>>(assignb, hist);
      scan_kernel<<<1, 256, 0, stream>>>(hist, base, counts, cbase);
      scatter_kernel<<<NPTS / 1024, 64, 0, stream>>>(assignb, base, perm);
      seg_sum_kernel<<<dim3(NK, SEG), 256, 0, stream>>>(x, perm, counts, cbase, partial);
      reduce_kernel<<<NK, 256, 0, stream>>>(partial, counts, c, c2);
    }
    assign_kernel<<<NPTS / 64, 256, 0, stream>>>(x, c, x2, c2, (int*)d_out);
  }
}

// Round 7
// 1028.927 us; speedup vs baseline: 1.0330x; 1.0330x over previous
//
#include <hip/hip_runtime.h>

#define NPTS 131072
#define DIM 256
#define NK 128
#define NITER 10
#define SEG 16       // fallback path only
#define TILE 128     // rows per balanced segment
#define MAXSEGS (NPTS / TILE + NK)  // 1152

typedef _Float16 half8 __attribute__((ext_vector_type(8)));
typedef _Float16 half4v __attribute__((ext_vector_type(4)));
typedef float f32x4 __attribute__((ext_vector_type(4)));

#define RSCALE 4096.0f
#define RINV 2.44140625e-4f  // 2^-12 exact

// ---------------------------------------------------------------------------
// x2[i] = sum_d x[i][d]^2   (16 threads per point)
// ---------------------------------------------------------------------------
__global__ void x2_kernel(const float* __restrict__ x, float* __restrict__ x2) {
  int tid = threadIdx.x;
  int p = blockIdx.x * 16 + (tid >> 4);
  int part = tid & 15;
  const float4* xr = (const float4*)(x + (size_t)p * DIM);
  float s = 0.f;
#pragma unroll
  for (int j = 0; j < 4; ++j) {
    float4 v = xr[part * 4 + j];
    s += v.x * v.x;
    s += v.y * v.y;
    s += v.z * v.z;
    s += v.w * v.w;
  }
#pragma unroll
  for (int m = 8; m >= 1; m >>= 1) s += __shfl_xor(s, m, 16);
  if (part == 0) x2[p] = s;
}

// ---------------------------------------------------------------------------
// c2[k] = sum_d c[k][d]^2   (one wave per cluster, init only)
// ---------------------------------------------------------------------------
__global__ void c2_kernel(const float* __restrict__ c, float* __restrict__ c2) {
  int k = blockIdx.x, lane = threadIdx.x;
  float4 v = ((const float4*)(c + (size_t)k * DIM))[lane];
  float s = v.x * v.x + v.y * v.y + v.z * v.z + v.w * v.w;
#pragma unroll
  for (int m = 32; m >= 1; m >>= 1) s += __shfl_xor(s, m, 64);
  if (lane == 0) c2[k] = s;
}

// ---------------------------------------------------------------------------
// fp32 -> (f16 hi, f16 scaled residual). a = hi + lo * 2^-12 + O(2^-22 a)
// ---------------------------------------------------------------------------
__global__ void convert_x_kernel(const float* __restrict__ x, _Float16* __restrict__ x1,
                                 _Float16* __restrict__ x2s) {
  int i = blockIdx.x * 256 + threadIdx.x;  // float4 index
  float4 v = ((const float4*)x)[i];
  float f[4] = {v.x, v.y, v.z, v.w};
  half4v h, l;
#pragma unroll
  for (int j = 0; j < 4; ++j) {
    _Float16 hi = (_Float16)f[j];
    float r = f[j] - (float)hi;
    h[j] = hi;
    l[j] = (_Float16)(r * RSCALE);
  }
  ((half4v*)x1)[i] = h;
  ((half4v*)x2s)[i] = l;
}

// ---------------------------------------------------------------------------
// centroids fp32 -> chunk-tiled f16 split layout (init only; reduce_kernel
// regenerates ct each iteration thereafter).
// ---------------------------------------------------------------------------
__global__ void convert_c_kernel(const float* __restrict__ c, _Float16* __restrict__ ct) {
  int i = blockIdx.x * 256 + threadIdx.x;  // float4 index, 8192 total
  int k = i >> 6;
  int d4 = i & 63;
  float4 v = ((const float4*)c)[i];
  float f[4] = {v.x, v.y, v.z, v.w};
  half4v h, l;
#pragma unroll
  for (int j = 0; j < 4; ++j) {
    _Float16 hi = (_Float16)f[j];
    float r = f[j] - (float)hi;
    h[j] = hi;
    l[j] = (_Float16)(r * RSCALE);
  }
  int ch = d4 >> 3;
  int idx4 = ch * 2048 + k * 8 + (d4 & 7);
  ((half4v*)ct)[idx4] = h;
  ((half4v*)ct)[idx4 + 1024] = l;
}

// ---------------------------------------------------------------------------
// MFMA assignment: 256 threads = 4 waves x 32 points = 128 points/block.
// Centroid chunk (32 dims, hi+lo = 16 KB) double-buffered in LDS.
// DOHIST: fused per-chunk histogram (int atomics -> deterministic).
// ---------------------------------------------------------------------------
template <bool DOHIST>
__global__ __launch_bounds__(256, 2) void assign_mfma_kernel(
    const _Float16* __restrict__ x1, const _Float16* __restrict__ x2s,
    const _Float16* __restrict__ ct, const float* __restrict__ x2,
    const float* __restrict__ c2, int* __restrict__ out, int* __restrict__ hist) {
  __shared__ __align__(16) _Float16 cbuf[2][8192];
  __shared__ int hcnt[NK];

  int tid = threadIdx.x;
  int lane = tid & 63;
  int w = tid >> 6;
  int lcol = lane & 15;
  int lgrp = lane >> 4;
  int row0 = blockIdx.x * 128 + w * 32;

  if (DOHIST && tid < NK) hcnt[tid] = 0;

  const _Float16* xa = x1 + (size_t)(row0 + lcol) * DIM + lgrp * 8;
  const _Float16* xb = x2s + (size_t)(row0 + lcol) * DIM + lgrp * 8;
  const half8* ctv = (const half8*)ct;

  f32x4 acc1[2][8], acc2[2][8];
#pragma unroll
  for (int rt = 0; rt < 2; ++rt)
#pragma unroll
    for (int c8 = 0; c8 < 8; ++c8) {
      acc1[rt][c8] = f32x4{0.f, 0.f, 0.f, 0.f};
      acc2[rt][c8] = f32x4{0.f, 0.f, 0.f, 0.f};
    }

  half8 A1[2], A2[2], nA1[2], nA2[2], sreg[4];

#pragma unroll
  for (int r = 0; r < 4; ++r) sreg[r] = ctv[r * 256 + tid];
#pragma unroll
  for (int rt = 0; rt < 2; ++rt) {
    A1[rt] = *(const half8*)(xa + rt * 16 * DIM);
    A2[rt] = *(const half8*)(xb + rt * 16 * DIM);
  }
#pragma unroll
  for (int r = 0; r < 4; ++r) ((half8*)cbuf[0])[r * 256 + tid] = sreg[r];
  __syncthreads();

#pragma unroll
  for (int ck = 0; ck < 8; ++ck) {
    const int cb = ck & 1;
    if (ck < 7) {
#pragma unroll
      for (int r = 0; r < 4; ++r) sreg[r] = ctv[(ck + 1) * 1024 + r * 256 + tid];
#pragma unroll
      for (int rt = 0; rt < 2; ++rt) {
        nA1[rt] = *(const half8*)(xa + rt * 16 * DIM + (ck + 1) * 32);
        nA2[rt] = *(const half8*)(xb + rt * 16 * DIM + (ck + 1) * 32);
      }
    }
#pragma unroll
    for (int c8 = 0; c8 < 8; ++c8) {
      int bidx = (c8 * 16 + lcol) * 32 + lgrp * 8;
      half8 b1 = *(const half8*)&cbuf[cb][bidx];
      half8 b2 = *(const half8*)&cbuf[cb][4096 + bidx];
#pragma unroll
      for (int rt = 0; rt < 2; ++rt) {
        acc1[rt][c8] = __builtin_amdgcn_mfma_f32_16x16x32_f16(A1[rt], b1, acc1[rt][c8], 0, 0, 0);
        acc2[rt][c8] = __builtin_amdgcn_mfma_f32_16x16x32_f16(A1[rt], b2, acc2[rt][c8], 0, 0, 0);
        acc2[rt][c8] = __builtin_amdgcn_mfma_f32_16x16x32_f16(A2[rt], b1, acc2[rt][c8], 0, 0, 0);
      }
    }
    if (ck < 7) {
#pragma unroll
      for (int r = 0; r < 4; ++r) ((half8*)cbuf[cb ^ 1])[r * 256 + tid] = sreg[r];
#pragma unroll
      for (int rt = 0; rt < 2; ++rt) {
        A1[rt] = nA1[rt];
        A2[rt] = nA2[rt];
      }
      __syncthreads();
    }
  }

#pragma unroll
  for (int rt = 0; rt < 2; ++rt) {
    int pbase = row0 + rt * 16 + lgrp * 4;
    float x2p[4];
#pragma unroll
    for (int r = 0; r < 4; ++r) x2p[r] = x2[pbase + r];
    float bv[4];
    int bk[4];
#pragma unroll
    for (int r = 0; r < 4; ++r) { bv[r] = 3.4e38f; bk[r] = 0; }
#pragma unroll
    for (int c8 = 0; c8 < 8; ++c8) {
      int kc = c8 * 16 + lcol;
      float c2k = c2[kc];
#pragma unroll
      for (int r = 0; r < 4; ++r) {
        float dot = fmaf(acc2[rt][c8][r], RINV, acc1[rt][c8][r]);
        float d = fmaf(-2.f, dot, x2p[r]) + c2k;
        if (d < bv[r]) { bv[r] = d; bk[r] = kc; }
      }
    }
#pragma unroll
    for (int m = 1; m <= 8; m <<= 1) {
#pragma unroll
      for (int r = 0; r < 4; ++r) {
        float ov = __shfl_xor(bv[r], m, 64);
        int ok = __shfl_xor(bk[r], m, 64);
        if (ov < bv[r] || (ov == bv[r] && ok < bk[r])) { bv[r] = ov; bk[r] = ok; }
      }
    }
    if (lcol == 0) {
#pragma unroll
      for (int r = 0; r < 4; ++r) {
        out[pbase + r] = bk[r];
        if (DOHIST) atomicAdd(&hcnt[bk[r]], 1);
      }
    }
  }

  if (DOHIST) {
    __syncthreads();
    if (tid < NK) {
      int v = hcnt[tid];
      if (v) atomicAdd(&hist[(blockIdx.x >> 3) * NK + tid], v);
    }
  }
}

// ---------------------------------------------------------------------------
// fp32 fallback assignment (R2-proven) used when ws is too small
// ---------------------------------------------------------------------------
__global__ void assign_kernel(const float* __restrict__ x, const float* __restrict__ c,
                              const float* __restrict__ x2, const float* __restrict__ c2,
                              int* __restrict__ assign_out) {
  __shared__ float4 xs4[64 * 4];
  __shared__ float4 cs4[128 * 4];
  __shared__ float redv[64][17];
  __shared__ int redk[64][17];

  int tid = threadIdx.x;
  int tx = tid & 15;
  int ty = tid >> 4;
  int row0 = blockIdx.x * 64;

  float acc[4][8];
#pragma unroll
  for (int a = 0; a < 4; ++a)
#pragma unroll
    for (int b = 0; b < 8; ++b) acc[a][b] = 0.f;

  for (int ck = 0; ck < 16; ++ck) {
    {
      int p = tid >> 2, d4 = tid & 3;
      float4 v = *(const float4*)(x + (size_t)(row0 + p) * DIM + ck * 16 + d4 * 4);
      xs4[p * 4 + (d4 ^ ((p >> 2) & 3))] = v;
    }
#pragma unroll
    for (int r = 0; r < 2; ++r) {
      int idx = tid + r * 256;
      int kk = idx >> 2, dd = idx & 3;
      float4 v = *(const float4*)(c + (size_t)kk * DIM + ck * 16 + dd * 4);
      cs4[kk * 4 + (dd ^ ((kk >> 3) & 3))] = v;
    }
    __syncthreads();
#pragma unroll
    for (int d4 = 0; d4 < 4; ++d4) {
      float4 xr[4], cr[8];
#pragma unroll
      for (int pp = 0; pp < 4; ++pp) xr[pp] = xs4[(tx * 4 + pp) * 4 + (d4 ^ (tx & 3))];
#pragma unroll
      for (int kk = 0; kk < 8; ++kk) cr[kk] = cs4[(ty * 8 + kk) * 4 + (d4 ^ (ty & 3))];
#pragma unroll
      for (int pp = 0; pp < 4; ++pp)
#pragma unroll
        for (int kk = 0; kk < 8; ++kk) {
          acc[pp][kk] = fmaf(xr[pp].x, cr[kk].x, acc[pp][kk]);
          acc[pp][kk] = fmaf(xr[pp].y, cr[kk].y, acc[pp][kk]);
          acc[pp][kk] = fmaf(xr[pp].z, cr[kk].z, acc[pp][kk]);
          acc[pp][kk] = fmaf(xr[pp].w, cr[kk].w, acc[pp][kk]);
        }
    }
    __syncthreads();
  }

  float x2p[4];
#pragma unroll
  for (int pp = 0; pp < 4; ++pp) x2p[pp] = x2[row0 + tx * 4 + pp];

  float bestv[4];
  int bestk[4];
#pragma unroll
  for (int pp = 0; pp < 4; ++pp) { bestv[pp] = 3.4e38f; bestk[pp] = 0; }
#pragma unroll
  for (int kk = 0; kk < 8; ++kk) {
    float c2k = c2[ty * 8 + kk];
#pragma unroll
    for (int pp = 0; pp < 4; ++pp) {
      float d = fmaf(-2.f, acc[pp][kk], x2p[pp]) + c2k;
      if (d < bestv[pp]) { bestv[pp] = d; bestk[pp] = ty * 8 + kk; }
    }
  }
#pragma unroll
  for (int pp = 0; pp < 4; ++pp) {
    redv[tx * 4 + pp][ty] = bestv[pp];
    redk[tx * 4 + pp][ty] = bestk[pp];
  }
  __syncthreads();
  if (tid < 64) {
    float bv = redv[tid][0];
    int bk = redk[tid][0];
#pragma unroll
    for (int t = 1; t < 16; ++t) {
      float v = redv[tid][t];
      if (v < bv) { bv = v; bk = redk[tid][t]; }
    }
    assign_out[row0 + tid] = bk;
  }
}

// ---------------------------------------------------------------------------
__global__ void hist_kernel(const int* __restrict__ assign_in, int* __restrict__ hist) {
  __shared__ int h[NK];
  int tid = threadIdx.x, b = blockIdx.x;
  if (tid < NK) h[tid] = 0;
  __syncthreads();
#pragma unroll
  for (int r = 0; r < 4; ++r) {
    int a = assign_in[b * 1024 + r * 256 + tid];
    atomicAdd(&h[a], 1);
  }
  __syncthreads();
  if (tid < NK) hist[b * NK + tid] = h[tid];
}

// ---------------------------------------------------------------------------
// Scan v2: chunk-exclusive prefix + cluster bases + balanced-segment bases.
// Also zeroes hist for the next iteration's fused-histogram assign.
// ---------------------------------------------------------------------------
__global__ void scan_kernel(int* __restrict__ hist, int* __restrict__ base,
                            int* __restrict__ counts, int* __restrict__ cbase,
                            int* __restrict__ segbase) {
  __shared__ int h[128 * NK];
  __shared__ int scnt[NK];
  __shared__ int scb[NK];
  __shared__ int ssb[NK + 1];
  int tid = threadIdx.x;
  for (int i = tid; i < 128 * NK; i += 256) h[i] = hist[i];
  __syncthreads();
  for (int i = tid; i < 128 * NK; i += 256) hist[i] = 0;  // re-zero for fused hist
  if (tid < NK) {
    int run = 0;
    for (int b = 0; b < 128; ++b) {
      int v = h[b * NK + tid];
      h[b * NK + tid] = run;
      run += v;
    }
    scnt[tid] = run;
    counts[tid] = run;
  }
  __syncthreads();
  if (tid == 0) {
    int cb = 0, sb = 0;
    for (int j = 0; j < NK; ++j) {
      scb[j] = cb;
      cb += scnt[j];
      ssb[j] = sb;
      sb += (scnt[j] + TILE - 1) / TILE;
    }
    ssb[NK] = sb;
  }
  __syncthreads();
  if (tid < NK) {
    cbase[tid] = scb[tid];
    int cbk = scb[tid];
    for (int b = 0; b < 128; ++b) base[b * NK + tid] = h[b * NK + tid] + cbk;
  }
  if (tid <= NK) segbase[tid] = ssb[tid];
}

// ---------------------------------------------------------------------------
// Stable scatter: 1 wave per chunk; wave-synchronous (no barriers needed).
// ---------------------------------------------------------------------------
__global__ void scatter_kernel(const int* __restrict__ assign_in, const int* __restrict__ base,
                               int* __restrict__ perm) {
  __shared__ int cnt[NK];
  int lane = threadIdx.x, b = blockIdx.x;
  cnt[lane] = base[b * NK + lane];
  cnt[lane + 64] = base[b * NK + lane + 64];
  for (int r = 0; r < 16; ++r) {
    int p = b * 1024 + r * 64 + lane;
    int a = assign_in[p];
    unsigned long long mask = ~0ull;
#pragma unroll
    for (int j = 0; j < 7; ++j) {
      unsigned long long bal = __ballot((a >> j) & 1);
      mask &= ((a >> j) & 1) ? bal : ~bal;
    }
    int rank = __popcll(mask & ((1ull << lane) - 1ull));
    int pos = cnt[a] + rank;
    perm[pos] = p;
    if (rank == 0) cnt[a] += (int)__popcll(mask);
  }
}

// ---------------------------------------------------------------------------
// seg_sum v3: balanced segments of TILE rows. Block b -> (cluster k, rows
// [j0,j1)) via binary search on segbase. perm values register-staged and
// __shfl-broadcast so the loop has only independent float4 row loads.
// ---------------------------------------------------------------------------
__global__ __launch_bounds__(256) void seg_sum_v3_kernel(
    const float* __restrict__ x, const int* __restrict__ perm,
    const int* __restrict__ counts, const int* __restrict__ cbase,
    const int* __restrict__ segbase, float* __restrict__ partial) {
  __shared__ int sb[NK + 1];
  __shared__ float4 red[4][64];
  int tid = threadIdx.x;
  if (tid <= NK) sb[tid] = segbase[tid];
  __syncthreads();
  int b = blockIdx.x;
  if (b >= sb[NK]) return;
  int lo = 0, hi = NK - 1;
  while (lo < hi) {
    int mid = (lo + hi + 1) >> 1;
    if (sb[mid] <= b) lo = mid;
    else hi = mid - 1;
  }
  int k = lo;
  int cnt = counts[k], off = cbase[k];
  int j0 = (b - sb[k]) * TILE;
  int j1 = min(j0 + TILE, cnt);

  int tg = tid >> 6;    // group 0..3
  int lane = tid & 63;  // float4 index within row
  int len = j1 - j0;
  int jj0 = j0 + (len * tg) / 4;
  int jj1 = j0 + (len * (tg + 1)) / 4;
  int n = jj1 - jj0;

  // stage this group's perm slice (<=32) into registers, broadcast via shfl
  int pv = 0;
  if (lane < n) pv = perm[off + jj0 + lane];

  float4 acc = {0.f, 0.f, 0.f, 0.f};
#pragma unroll 4
  for (int j = 0; j < n; ++j) {
    int p = __shfl(pv, j, 64);
    float4 v = ((const float4*)(x + (size_t)p * DIM))[lane];
    acc.x += v.x;
    acc.y += v.y;
    acc.z += v.z;
    acc.w += v.w;
  }
  red[tg][lane] = acc;
  __syncthreads();
  if (tg == 0) {
    float4 s0 = red[0][lane], s1 = red[1][lane], s2 = red[2][lane], s3 = red[3][lane];
    float4 t;
    t.x = ((s0.x + s1.x) + s2.x) + s3.x;
    t.y = ((s0.y + s1.y) + s2.y) + s3.y;
    t.z = ((s0.z + s1.z) + s2.z) + s3.z;
    t.w = ((s0.w + s1.w) + s2.w) + s3.w;
    ((float4*)(partial + (size_t)b * DIM))[lane] = t;
  }
}

// ---------------------------------------------------------------------------
// Reduce v2: variable segment count per cluster, fixed order (deterministic).
// Also regenerates c2 and the chunk-tiled f16-split ct (fuses convert_c).
// ---------------------------------------------------------------------------
__global__ void reduce_kernel(const float* __restrict__ partial, const int* __restrict__ counts,
                              const int* __restrict__ segbase, float* __restrict__ c,
                              float* __restrict__ c2, _Float16* __restrict__ ct) {
  __shared__ float wsum[4];
  int k = blockIdx.x, d = threadIdx.x;
  int cnt = counts[k];
  int s0 = segbase[k], s1 = segbase[k + 1];
  float s = 0.f;
  int t = s0;
  for (; t + 4 <= s1; t += 4) {
    float p0 = partial[(size_t)(t + 0) * DIM + d];
    float p1 = partial[(size_t)(t + 1) * DIM + d];
    float p2 = partial[(size_t)(t + 2) * DIM + d];
    float p3 = partial[(size_t)(t + 3) * DIM + d];
    s += ((p0 + p1) + p2) + p3;
  }
  for (; t < s1; ++t) s += partial[(size_t)t * DIM + d];

  float nc;
  if (cnt > 0)
    nc = s / fmaxf((float)cnt, 1.0f);
  else
    nc = c[(size_t)k * DIM + d];
  c[(size_t)k * DIM + d] = nc;

  // fused convert_c: chunk-tiled f16 split
  {
    _Float16 hi = (_Float16)nc;
    float r = nc - (float)hi;
    _Float16 lov = (_Float16)(r * RSCALE);
    int ch = d >> 5, dd = d & 31;
    ct[ch * 8192 + k * 32 + dd] = hi;
    ct[ch * 8192 + k * 32 + dd + 4096] = lov;
  }

  float s2 = nc * nc;
#pragma unroll
  for (int m = 32; m >= 1; m >>= 1) s2 += __shfl_xor(s2, m, 64);
  if ((threadIdx.x & 63) == 0) wsum[threadIdx.x >> 6] = s2;
  __syncthreads();
  if (threadIdx.x == 0) c2[k] = wsum[0] + wsum[1] + wsum[2] + wsum[3];
}

// ---------------------------------------------------------------------------
// fallback seg_sum/reduce (fp32, SEG fixed) -- R2-proven path
// ---------------------------------------------------------------------------
__global__ void seg_sum_kernel(const float* __restrict__ x, const int* __restrict__ perm,
                               const int* __restrict__ counts, const int* __restrict__ cbase,
                               float* __restrict__ partial) {
  int k = blockIdx.x, s = blockIdx.y, d = threadIdx.x;
  int cnt = counts[k], off = cbase[k];
  int j0 = (int)(((long long)cnt * s) / SEG);
  int j1 = (int)(((long long)cnt * (s + 1)) / SEG);
  float sum = 0.f;
  int j = j0;
  for (; j + 4 <= j1; j += 4) {
    int p0 = perm[off + j + 0];
    int p1 = perm[off + j + 1];
    int p2 = perm[off + j + 2];
    int p3 = perm[off + j + 3];
    sum += x[(size_t)p0 * DIM + d];
    sum += x[(size_t)p1 * DIM + d];
    sum += x[(size_t)p2 * DIM + d];
    sum += x[(size_t)p3 * DIM + d];
  }
  for (; j < j1; ++j) sum += x[(size_t)perm[off + j] * DIM + d];
  partial[((size_t)k * SEG + s) * DIM + d] = sum;
}

__global__ void reduce_fb_kernel(const float* __restrict__ partial, const int* __restrict__ counts,
                                 float* __restrict__ c, float* __restrict__ c2) {
  __shared__ float wsum[4];
  int k = blockIdx.x, d = threadIdx.x;
  int cnt = counts[k];
  float s = 0.f;
#pragma unroll
  for (int t = 0; t < SEG; ++t) s += partial[((size_t)k * SEG + t) * DIM + d];
  float nc;
  if (cnt > 0)
    nc = s / fmaxf((float)cnt, 1.0f);
  else
    nc = c[(size_t)k * DIM + d];
  c[(size_t)k * DIM + d] = nc;
  float s2 = nc * nc;
#pragma unroll
  for (int m = 32; m >= 1; m >>= 1) s2 += __shfl_xor(s2, m, 64);
  if ((threadIdx.x & 63) == 0) wsum[threadIdx.x >> 6] = s2;
  __syncthreads();
  if (threadIdx.x == 0) c2[k] = wsum[0] + wsum[1] + wsum[2] + wsum[3];
}

__global__ void scan_fb_kernel(const int* __restrict__ hist, int* __restrict__ base,
                               int* __restrict__ counts, int* __restrict__ cbase) {
  __shared__ int h[128 * NK];
  int tid = threadIdx.x;
  for (int i = tid; i < 128 * NK; i += 256) h[i] = hist[i];
  __syncthreads();
  if (tid < NK) {
    int run = 0;
    for (int b = 0; b < 128; ++b) {
      int v = h[b * NK + tid];
      h[b * NK + tid] = run;
      run += v;
    }
    counts[tid] = run;
  }
  __syncthreads();
  if (tid == 0) {
    int cb = 0;
    for (int j = 0; j < NK; ++j) {
      cbase[j] = cb;
      cb += counts[j];
    }
  }
  __syncthreads();
  if (tid < NK) {
    int cbk = cbase[tid];
    for (int b = 0; b < 128; ++b) base[b * NK + tid] = h[b * NK + tid] + cbk;
  }
}

// ---------------------------------------------------------------------------
extern "C" void kernel_launch(void* const* d_in, const int* in_sizes, int n_in,
                              void* d_out, int out_size, void* d_ws, size_t ws_size,
                              hipStream_t stream) {
  const float* x = (const float*)d_in[0];
  char* ws = (char*)d_ws;

  const size_t NEED_BIG = 138283520;
  bool use_mfma = ws_size >= NEED_BIG;

  if (use_mfma) {
    _Float16* x1 = (_Float16*)(ws + 0);           // 64 MB
    _Float16* x2s = (_Float16*)(ws + 67108864);   // 64 MB
    float* c = (float*)(ws + 134217728);          // 128 KB (fp32 centroids)
    _Float16* ct = (_Float16*)(ws + 134348800);   // 128 KB (chunk-tiled split)
    float* c2 = (float*)(ws + 134479872);         // 512 B
    float* x2 = (float*)(ws + 134480384);         // 512 KB
    int* assignb = (int*)(ws + 135004672);        // 512 KB
    int* hist = (int*)(ws + 135528960);           // 64 KB
    int* base = (int*)(ws + 135594496);           // 64 KB
    int* counts = (int*)(ws + 135660032);         // 512 B
    int* cbase = (int*)(ws + 135660544);          // 512 B
    int* perm = (int*)(ws + 135661056);           // 512 KB
    float* partial = (float*)(ws + 136185344);    // 2 MB (>= MAXSEGS*DIM*4 = 1.18 MB)
    int* segbase = (int*)(ws + 138282496);        // 1 KB (129 ints)

    hipMemcpyAsync(c, x, (size_t)NK * DIM * sizeof(float), hipMemcpyDeviceToDevice, stream);
    hipMemsetAsync(hist, 0, 128 * NK * sizeof(int), stream);
    convert_x_kernel<<<NPTS * DIM / 4 / 256, 256, 0, stream>>>(x, x1, x2s);
    x2_kernel<<<NPTS / 16, 256, 0, stream>>>(x, x2);
    c2_kernel<<<NK, 64, 0, stream>>>(c, c2);
    convert_c_kernel<<<NK * DIM / 4 / 256, 256, 0, stream>>>(c, ct);

    for (int it = 0; it < NITER; ++it) {
      assign_mfma_kernel<true><<<NPTS / 128, 256, 0, stream>>>(x1, x2s, ct, x2, c2, assignb, hist);
      scan_kernel<<<1, 256, 0, stream>>>(hist, base, counts, cbase, segbase);
      scatter_kernel<<<NPTS / 1024, 64, 0, stream>>>(assignb, base, perm);
      seg_sum_v3_kernel<<<MAXSEGS, 256, 0, stream>>>(x, perm, counts, cbase, segbase, partial);
      reduce_kernel<<<NK, 256, 0, stream>>>(partial, counts, segbase, c, c2, ct);
    }
    assign_mfma_kernel<false><<<NPTS / 128, 256, 0, stream>>>(x1, x2s, ct, x2, c2, (int*)d_out,
                                                              hist);
  } else {
    float* c = (float*)(ws + 0);
    float* c2 = (float*)(ws + 131072);
    float* x2 = (float*)(ws + 132096);
    int* assignb = (int*)(ws + 656384);
    int* hist = (int*)(ws + 1180672);
    int* base = (int*)(ws + 1246208);
    int* counts = (int*)(ws + 1311744);
    int* cbase = (int*)(ws + 1312256);
    int* perm = (int*)(ws + 1312768);
    float* partial = (float*)(ws + 1837056);

    hipMemcpyAsync(c, x, (size_t)NK * DIM * sizeof(float), hipMemcpyDeviceToDevice, stream);
    x2_kernel<<<NPTS / 16, 256, 0, stream>>>(x, x2);
    c2_kernel<<<NK, 64, 0, stream>>>(c, c2);

    for (int it = 0; it < NITER; ++it) {
      assign_kernel<<<NPTS / 64, 256, 0, stream>>>(x, c, x2, c2, assignb);
      hist_kernel<<<NPTS / 1024, 256, 0, stream>>>(assignb, hist);
      scan_fb_kernel<<<1, 256, 0, stream>>>(hist, base, counts, cbase);
      scatter_kernel<<<NPTS / 1024, 64, 0, stream>>>(assignb, base, perm);
      seg_sum_kernel<<<dim3(NK, SEG), 256, 0, stream>>>(x, perm, counts, cbase, partial);
      reduce_fb_kernel<<<NK, 256, 0, stream>>>(partial, counts, c, c2);
    }
    assign_kernel<<<NPTS / 64, 256, 0, stream>>>(x, c, x2, c2, (int*)d_out);
  }
}

// Round 8
// 993.469 us; speedup vs baseline: 1.0699x; 1.0357x over previous
//
#include <hip/hip_runtime.h>

#define NPTS 131072
#define DIM 256
#define NK 128
#define NITER 10
#define SEG 16       // fallback path only
#define TILE 128     // rows per balanced segment
#define MAXSEGS (NPTS / TILE + NK)  // 1152

typedef _Float16 half8 __attribute__((ext_vector_type(8)));
typedef _Float16 half4v __attribute__((ext_vector_type(4)));
typedef float f32x4 __attribute__((ext_vector_type(4)));

#define RSCALE 4096.0f
#define RINV 2.44140625e-4f  // 2^-12 exact

// ---------------------------------------------------------------------------
// x2[i] = sum_d x[i][d]^2   (fallback-path setup)
// ---------------------------------------------------------------------------
__global__ void x2_kernel(const float* __restrict__ x, float* __restrict__ x2) {
  int tid = threadIdx.x;
  int p = blockIdx.x * 16 + (tid >> 4);
  int part = tid & 15;
  const float4* xr = (const float4*)(x + (size_t)p * DIM);
  float s = 0.f;
#pragma unroll
  for (int j = 0; j < 4; ++j) {
    float4 v = xr[part * 4 + j];
    s += v.x * v.x;
    s += v.y * v.y;
    s += v.z * v.z;
    s += v.w * v.w;
  }
#pragma unroll
  for (int m = 8; m >= 1; m >>= 1) s += __shfl_xor(s, m, 16);
  if (part == 0) x2[p] = s;
}

// ---------------------------------------------------------------------------
// c2[k] = sum_d c[k][d]^2   (one wave per cluster, init only)
// ---------------------------------------------------------------------------
__global__ void c2_kernel(const float* __restrict__ c, float* __restrict__ c2) {
  int k = blockIdx.x, lane = threadIdx.x;
  float4 v = ((const float4*)(c + (size_t)k * DIM))[lane];
  float s = v.x * v.x + v.y * v.y + v.z * v.z + v.w * v.w;
#pragma unroll
  for (int m = 32; m >= 1; m >>= 1) s += __shfl_xor(s, m, 64);
  if (lane == 0) c2[k] = s;
}

// ---------------------------------------------------------------------------
// Fused: fp32 x -> (f16 hi, f16 scaled residual) AND x2 row-sums.
// One 134 MB read pass instead of two. x2 accumulation order identical to
// x2_kernel (16 threads/point, 4 sequential float4 each, shfl-16 reduce).
// ---------------------------------------------------------------------------
__global__ void convert_x2_kernel(const float* __restrict__ x, _Float16* __restrict__ x1,
                                  _Float16* __restrict__ x2s, float* __restrict__ x2) {
  int tid = threadIdx.x;
  int p = blockIdx.x * 16 + (tid >> 4);
  int part = tid & 15;
  const float4* xr = (const float4*)(x + (size_t)p * DIM);
  half4v* o1 = (half4v*)(x1 + (size_t)p * DIM);
  half4v* o2 = (half4v*)(x2s + (size_t)p * DIM);
  float s = 0.f;
#pragma unroll
  for (int j = 0; j < 4; ++j) {
    float4 v = xr[part * 4 + j];
    float f[4] = {v.x, v.y, v.z, v.w};
    half4v h, l;
#pragma unroll
    for (int u = 0; u < 4; ++u) {
      _Float16 hi = (_Float16)f[u];
      float r = f[u] - (float)hi;
      h[u] = hi;
      l[u] = (_Float16)(r * RSCALE);
      s += f[u] * f[u];
    }
    o1[part * 4 + j] = h;
    o2[part * 4 + j] = l;
  }
#pragma unroll
  for (int m = 8; m >= 1; m >>= 1) s += __shfl_xor(s, m, 16);
  if (part == 0) x2[p] = s;
}

// ---------------------------------------------------------------------------
// centroids fp32 -> chunk-tiled f16 split layout (init only; reduce_kernel
// regenerates ct each iteration thereafter).
// ---------------------------------------------------------------------------
__global__ void convert_c_kernel(const float* __restrict__ c, _Float16* __restrict__ ct) {
  int i = blockIdx.x * 256 + threadIdx.x;  // float4 index, 8192 total
  int k = i >> 6;
  int d4 = i & 63;
  float4 v = ((const float4*)c)[i];
  float f[4] = {v.x, v.y, v.z, v.w};
  half4v h, l;
#pragma unroll
  for (int j = 0; j < 4; ++j) {
    _Float16 hi = (_Float16)f[j];
    float r = f[j] - (float)hi;
    h[j] = hi;
    l[j] = (_Float16)(r * RSCALE);
  }
  int ch = d4 >> 3;
  int idx4 = ch * 2048 + k * 8 + (d4 & 7);
  ((half4v*)ct)[idx4] = h;
  ((half4v*)ct)[idx4 + 1024] = l;
}

// ---------------------------------------------------------------------------
// MFMA assignment: 256 threads = 4 waves x 32 points = 128 points/block.
// Centroid chunk (32 dims, hi+lo = 16 KB) double-buffered in LDS.
// DOHIST: fused per-chunk histogram (int atomics -> deterministic).
// ---------------------------------------------------------------------------
template <bool DOHIST>
__global__ __launch_bounds__(256, 2) void assign_mfma_kernel(
    const _Float16* __restrict__ x1, const _Float16* __restrict__ x2s,
    const _Float16* __restrict__ ct, const float* __restrict__ x2,
    const float* __restrict__ c2, int* __restrict__ out, int* __restrict__ hist) {
  __shared__ __align__(16) _Float16 cbuf[2][8192];
  __shared__ int hcnt[NK];

  int tid = threadIdx.x;
  int lane = tid & 63;
  int w = tid >> 6;
  int lcol = lane & 15;
  int lgrp = lane >> 4;
  int row0 = blockIdx.x * 128 + w * 32;

  if (DOHIST && tid < NK) hcnt[tid] = 0;

  const _Float16* xa = x1 + (size_t)(row0 + lcol) * DIM + lgrp * 8;
  const _Float16* xb = x2s + (size_t)(row0 + lcol) * DIM + lgrp * 8;
  const half8* ctv = (const half8*)ct;

  f32x4 acc1[2][8], acc2[2][8];
#pragma unroll
  for (int rt = 0; rt < 2; ++rt)
#pragma unroll
    for (int c8 = 0; c8 < 8; ++c8) {
      acc1[rt][c8] = f32x4{0.f, 0.f, 0.f, 0.f};
      acc2[rt][c8] = f32x4{0.f, 0.f, 0.f, 0.f};
    }

  half8 A1[2], A2[2], nA1[2], nA2[2], sreg[4];

#pragma unroll
  for (int r = 0; r < 4; ++r) sreg[r] = ctv[r * 256 + tid];
#pragma unroll
  for (int rt = 0; rt < 2; ++rt) {
    A1[rt] = *(const half8*)(xa + rt * 16 * DIM);
    A2[rt] = *(const half8*)(xb + rt * 16 * DIM);
  }
#pragma unroll
  for (int r = 0; r < 4; ++r) ((half8*)cbuf[0])[r * 256 + tid] = sreg[r];
  __syncthreads();

#pragma unroll
  for (int ck = 0; ck < 8; ++ck) {
    const int cb = ck & 1;
    if (ck < 7) {
#pragma unroll
      for (int r = 0; r < 4; ++r) sreg[r] = ctv[(ck + 1) * 1024 + r * 256 + tid];
#pragma unroll
      for (int rt = 0; rt < 2; ++rt) {
        nA1[rt] = *(const half8*)(xa + rt * 16 * DIM + (ck + 1) * 32);
        nA2[rt] = *(const half8*)(xb + rt * 16 * DIM + (ck + 1) * 32);
      }
    }
#pragma unroll
    for (int c8 = 0; c8 < 8; ++c8) {
      int bidx = (c8 * 16 + lcol) * 32 + lgrp * 8;
      half8 b1 = *(const half8*)&cbuf[cb][bidx];
      half8 b2 = *(const half8*)&cbuf[cb][4096 + bidx];
#pragma unroll
      for (int rt = 0; rt < 2; ++rt) {
        acc1[rt][c8] = __builtin_amdgcn_mfma_f32_16x16x32_f16(A1[rt], b1, acc1[rt][c8], 0, 0, 0);
        acc2[rt][c8] = __builtin_amdgcn_mfma_f32_16x16x32_f16(A1[rt], b2, acc2[rt][c8], 0, 0, 0);
        acc2[rt][c8] = __builtin_amdgcn_mfma_f32_16x16x32_f16(A2[rt], b1, acc2[rt][c8], 0, 0, 0);
      }
    }
    if (ck < 7) {
#pragma unroll
      for (int r = 0; r < 4; ++r) ((half8*)cbuf[cb ^ 1])[r * 256 + tid] = sreg[r];
#pragma unroll
      for (int rt = 0; rt < 2; ++rt) {
        A1[rt] = nA1[rt];
        A2[rt] = nA2[rt];
      }
      __syncthreads();
    }
  }

#pragma unroll
  for (int rt = 0; rt < 2; ++rt) {
    int pbase = row0 + rt * 16 + lgrp * 4;
    float x2p[4];
#pragma unroll
    for (int r = 0; r < 4; ++r) x2p[r] = x2[pbase + r];
    float bv[4];
    int bk[4];
#pragma unroll
    for (int r = 0; r < 4; ++r) { bv[r] = 3.4e38f; bk[r] = 0; }
#pragma unroll
    for (int c8 = 0; c8 < 8; ++c8) {
      int kc = c8 * 16 + lcol;
      float c2k = c2[kc];
#pragma unroll
      for (int r = 0; r < 4; ++r) {
        float dot = fmaf(acc2[rt][c8][r], RINV, acc1[rt][c8][r]);
        float d = fmaf(-2.f, dot, x2p[r]) + c2k;
        if (d < bv[r]) { bv[r] = d; bk[r] = kc; }
      }
    }
#pragma unroll
    for (int m = 1; m <= 8; m <<= 1) {
#pragma unroll
      for (int r = 0; r < 4; ++r) {
        float ov = __shfl_xor(bv[r], m, 64);
        int ok = __shfl_xor(bk[r], m, 64);
        if (ov < bv[r] || (ov == bv[r] && ok < bk[r])) { bv[r] = ov; bk[r] = ok; }
      }
    }
    if (lcol == 0) {
#pragma unroll
      for (int r = 0; r < 4; ++r) {
        out[pbase + r] = bk[r];
        if (DOHIST) atomicAdd(&hcnt[bk[r]], 1);
      }
    }
  }

  if (DOHIST) {
    __syncthreads();
    if (tid < NK) {
      int v = hcnt[tid];
      if (v) atomicAdd(&hist[(blockIdx.x >> 3) * NK + tid], v);
    }
  }
}

// ---------------------------------------------------------------------------
// fp32 fallback assignment (R2-proven) used when ws is too small
// ---------------------------------------------------------------------------
__global__ void assign_kernel(const float* __restrict__ x, const float* __restrict__ c,
                              const float* __restrict__ x2, const float* __restrict__ c2,
                              int* __restrict__ assign_out) {
  __shared__ float4 xs4[64 * 4];
  __shared__ float4 cs4[128 * 4];
  __shared__ float redv[64][17];
  __shared__ int redk[64][17];

  int tid = threadIdx.x;
  int tx = tid & 15;
  int ty = tid >> 4;
  int row0 = blockIdx.x * 64;

  float acc[4][8];
#pragma unroll
  for (int a = 0; a < 4; ++a)
#pragma unroll
    for (int b = 0; b < 8; ++b) acc[a][b] = 0.f;

  for (int ck = 0; ck < 16; ++ck) {
    {
      int p = tid >> 2, d4 = tid & 3;
      float4 v = *(const float4*)(x + (size_t)(row0 + p) * DIM + ck * 16 + d4 * 4);
      xs4[p * 4 + (d4 ^ ((p >> 2) & 3))] = v;
    }
#pragma unroll
    for (int r = 0; r < 2; ++r) {
      int idx = tid + r * 256;
      int kk = idx >> 2, dd = idx & 3;
      float4 v = *(const float4*)(c + (size_t)kk * DIM + ck * 16 + dd * 4);
      cs4[kk * 4 + (dd ^ ((kk >> 3) & 3))] = v;
    }
    __syncthreads();
#pragma unroll
    for (int d4 = 0; d4 < 4; ++d4) {
      float4 xr[4], cr[8];
#pragma unroll
      for (int pp = 0; pp < 4; ++pp) xr[pp] = xs4[(tx * 4 + pp) * 4 + (d4 ^ (tx & 3))];
#pragma unroll
      for (int kk = 0; kk < 8; ++kk) cr[kk] = cs4[(ty * 8 + kk) * 4 + (d4 ^ (ty & 3))];
#pragma unroll
      for (int pp = 0; pp < 4; ++pp)
#pragma unroll
        for (int kk = 0; kk < 8; ++kk) {
          acc[pp][kk] = fmaf(xr[pp].x, cr[kk].x, acc[pp][kk]);
          acc[pp][kk] = fmaf(xr[pp].y, cr[kk].y, acc[pp][kk]);
          acc[pp][kk] = fmaf(xr[pp].z, cr[kk].z, acc[pp][kk]);
          acc[pp][kk] = fmaf(xr[pp].w, cr[kk].w, acc[pp][kk]);
        }
    }
    __syncthreads();
  }

  float x2p[4];
#pragma unroll
  for (int pp = 0; pp < 4; ++pp) x2p[pp] = x2[row0 + tx * 4 + pp];

  float bestv[4];
  int bestk[4];
#pragma unroll
  for (int pp = 0; pp < 4; ++pp) { bestv[pp] = 3.4e38f; bestk[pp] = 0; }
#pragma unroll
  for (int kk = 0; kk < 8; ++kk) {
    float c2k = c2[ty * 8 + kk];
#pragma unroll
    for (int pp = 0; pp < 4; ++pp) {
      float d = fmaf(-2.f, acc[pp][kk], x2p[pp]) + c2k;
      if (d < bestv[pp]) { bestv[pp] = d; bestk[pp] = ty * 8 + kk; }
    }
  }
#pragma unroll
  for (int pp = 0; pp < 4; ++pp) {
    redv[tx * 4 + pp][ty] = bestv[pp];
    redk[tx * 4 + pp][ty] = bestk[pp];
  }
  __syncthreads();
  if (tid < 64) {
    float bv = redv[tid][0];
    int bk = redk[tid][0];
#pragma unroll
    for (int t = 1; t < 16; ++t) {
      float v = redv[tid][t];
      if (v < bv) { bv = v; bk = redk[tid][t]; }
    }
    assign_out[row0 + tid] = bk;
  }
}

// ---------------------------------------------------------------------------
__global__ void hist_kernel(const int* __restrict__ assign_in, int* __restrict__ hist) {
  __shared__ int h[NK];
  int tid = threadIdx.x, b = blockIdx.x;
  if (tid < NK) h[tid] = 0;
  __syncthreads();
#pragma unroll
  for (int r = 0; r < 4; ++r) {
    int a = assign_in[b * 1024 + r * 256 + tid];
    atomicAdd(&h[a], 1);
  }
  __syncthreads();
  if (tid < NK) hist[b * NK + tid] = h[tid];
}

// ---------------------------------------------------------------------------
// Scan v2: chunk-exclusive prefix + cluster bases + balanced-segment bases.
// Also zeroes hist for the next iteration's fused-histogram assign.
// ---------------------------------------------------------------------------
__global__ void scan_kernel(int* __restrict__ hist, int* __restrict__ base,
                            int* __restrict__ counts, int* __restrict__ cbase,
                            int* __restrict__ segbase) {
  __shared__ int h[128 * NK];
  __shared__ int scnt[NK];
  __shared__ int scb[NK];
  __shared__ int ssb[NK + 1];
  int tid = threadIdx.x;
  for (int i = tid; i < 128 * NK; i += 256) h[i] = hist[i];
  __syncthreads();
  for (int i = tid; i < 128 * NK; i += 256) hist[i] = 0;  // re-zero for fused hist
  if (tid < NK) {
    int run = 0;
    for (int b = 0; b < 128; ++b) {
      int v = h[b * NK + tid];
      h[b * NK + tid] = run;
      run += v;
    }
    scnt[tid] = run;
    counts[tid] = run;
  }
  __syncthreads();
  if (tid == 0) {
    int cb = 0, sb = 0;
    for (int j = 0; j < NK; ++j) {
      scb[j] = cb;
      cb += scnt[j];
      ssb[j] = sb;
      sb += (scnt[j] + TILE - 1) / TILE;
    }
    ssb[NK] = sb;
  }
  __syncthreads();
  if (tid < NK) {
    cbase[tid] = scb[tid];
    int cbk = scb[tid];
    for (int b = 0; b < 128; ++b) base[b * NK + tid] = h[b * NK + tid] + cbk;
  }
  if (tid <= NK) segbase[tid] = ssb[tid];
}

// ---------------------------------------------------------------------------
// Stable scatter: 1 wave per chunk; wave-synchronous (no barriers needed).
// ---------------------------------------------------------------------------
__global__ void scatter_kernel(const int* __restrict__ assign_in, const int* __restrict__ base,
                               int* __restrict__ perm) {
  __shared__ int cnt[NK];
  int lane = threadIdx.x, b = blockIdx.x;
  cnt[lane] = base[b * NK + lane];
  cnt[lane + 64] = base[b * NK + lane + 64];
  for (int r = 0; r < 16; ++r) {
    int p = b * 1024 + r * 64 + lane;
    int a = assign_in[p];
    unsigned long long mask = ~0ull;
#pragma unroll
    for (int j = 0; j < 7; ++j) {
      unsigned long long bal = __ballot((a >> j) & 1);
      mask &= ((a >> j) & 1) ? bal : ~bal;
    }
    int rank = __popcll(mask & ((1ull << lane) - 1ull));
    int pos = cnt[a] + rank;
    perm[pos] = p;
    if (rank == 0) cnt[a] += (int)__popcll(mask);
  }
}

// ---------------------------------------------------------------------------
// seg_sum v4: balanced TILE-row segments (R7-proven structure) reading the
// f16 split pair (L3-shared with assign; fp32 x stays cold after setup).
// Per-element math acc += fmaf(lo, RINV, hi) == R5-proven reconstruct.
// ---------------------------------------------------------------------------
__global__ __launch_bounds__(256) void seg_sum_v4_kernel(
    const _Float16* __restrict__ x1, const _Float16* __restrict__ x2s,
    const int* __restrict__ perm, const int* __restrict__ counts,
    const int* __restrict__ cbase, const int* __restrict__ segbase,
    float* __restrict__ partial) {
  __shared__ int sb[NK + 1];
  __shared__ float4 red[4][64];
  int tid = threadIdx.x;
  if (tid <= NK) sb[tid] = segbase[tid];
  __syncthreads();
  int b = blockIdx.x;
  if (b >= sb[NK]) return;
  int lo = 0, hi = NK - 1;
  while (lo < hi) {
    int mid = (lo + hi + 1) >> 1;
    if (sb[mid] <= b) lo = mid;
    else hi = mid - 1;
  }
  int k = lo;
  int cnt = counts[k], off = cbase[k];
  int j0 = (b - sb[k]) * TILE;
  int j1 = min(j0 + TILE, cnt);

  int tg = tid >> 6;    // group 0..3
  int lane = tid & 63;  // half4v index within row (4 dims/lane)
  int len = j1 - j0;
  int jj0 = j0 + (len * tg) / 4;
  int jj1 = j0 + (len * (tg + 1)) / 4;
  int n = jj1 - jj0;

  int pv = 0;
  if (lane < n) pv = perm[off + jj0 + lane];

  float4 acc = {0.f, 0.f, 0.f, 0.f};
#pragma unroll 4
  for (int j = 0; j < n; ++j) {
    int p = __shfl(pv, j, 64);
    half4v h = ((const half4v*)(x1 + (size_t)p * DIM))[lane];
    half4v l = ((const half4v*)(x2s + (size_t)p * DIM))[lane];
    acc.x += fmaf((float)l[0], RINV, (float)h[0]);
    acc.y += fmaf((float)l[1], RINV, (float)h[1]);
    acc.z += fmaf((float)l[2], RINV, (float)h[2]);
    acc.w += fmaf((float)l[3], RINV, (float)h[3]);
  }
  red[tg][lane] = acc;
  __syncthreads();
  if (tg == 0) {
    float4 s0 = red[0][lane], s1 = red[1][lane], s2 = red[2][lane], s3 = red[3][lane];
    float4 t;
    t.x = ((s0.x + s1.x) + s2.x) + s3.x;
    t.y = ((s0.y + s1.y) + s2.y) + s3.y;
    t.z = ((s0.z + s1.z) + s2.z) + s3.z;
    t.w = ((s0.w + s1.w) + s2.w) + s3.w;
    ((float4*)(partial + (size_t)b * DIM))[lane] = t;
  }
}

// ---------------------------------------------------------------------------
// Reduce v2: variable segment count per cluster, fixed order (deterministic).
// Also regenerates c2 and the chunk-tiled f16-split ct (fuses convert_c).
// ---------------------------------------------------------------------------
__global__ void reduce_kernel(const float* __restrict__ partial, const int* __restrict__ counts,
                              const int* __restrict__ segbase, float* __restrict__ c,
                              float* __restrict__ c2, _Float16* __restrict__ ct) {
  __shared__ float wsum[4];
  int k = blockIdx.x, d = threadIdx.x;
  int cnt = counts[k];
  int s0 = segbase[k], s1 = segbase[k + 1];
  float s = 0.f;
  int t = s0;
  for (; t + 4 <= s1; t += 4) {
    float p0 = partial[(size_t)(t + 0) * DIM + d];
    float p1 = partial[(size_t)(t + 1) * DIM + d];
    float p2 = partial[(size_t)(t + 2) * DIM + d];
    float p3 = partial[(size_t)(t + 3) * DIM + d];
    s += ((p0 + p1) + p2) + p3;
  }
  for (; t < s1; ++t) s += partial[(size_t)t * DIM + d];

  float nc;
  if (cnt > 0)
    nc = s / fmaxf((float)cnt, 1.0f);
  else
    nc = c[(size_t)k * DIM + d];
  c[(size_t)k * DIM + d] = nc;

  // fused convert_c: chunk-tiled f16 split
  {
    _Float16 hi = (_Float16)nc;
    float r = nc - (float)hi;
    _Float16 lov = (_Float16)(r * RSCALE);
    int ch = d >> 5, dd = d & 31;
    ct[ch * 8192 + k * 32 + dd] = hi;
    ct[ch * 8192 + k * 32 + dd + 4096] = lov;
  }

  float s2 = nc * nc;
#pragma unroll
  for (int m = 32; m >= 1; m >>= 1) s2 += __shfl_xor(s2, m, 64);
  if ((threadIdx.x & 63) == 0) wsum[threadIdx.x >> 6] = s2;
  __syncthreads();
  if (threadIdx.x == 0) c2[k] = wsum[0] + wsum[1] + wsum[2] + wsum[3];
}

// ---------------------------------------------------------------------------
// fallback seg_sum/reduce/scan (fp32, SEG fixed) -- R2-proven path
// ---------------------------------------------------------------------------
__global__ void seg_sum_kernel(const float* __restrict__ x, const int* __restrict__ perm,
                               const int* __restrict__ counts, const int* __restrict__ cbase,
                               float* __restrict__ partial) {
  int k = blockIdx.x, s = blockIdx.y, d = threadIdx.x;
  int cnt = counts[k], off = cbase[k];
  int j0 = (int)(((long long)cnt * s) / SEG);
  int j1 = (int)(((long long)cnt * (s + 1)) / SEG);
  float sum = 0.f;
  int j = j0;
  for (; j + 4 <= j1; j += 4) {
    int p0 = perm[off + j + 0];
    int p1 = perm[off + j + 1];
    int p2 = perm[off + j + 2];
    int p3 = perm[off + j + 3];
    sum += x[(size_t)p0 * DIM + d];
    sum += x[(size_t)p1 * DIM + d];
    sum += x[(size_t)p2 * DIM + d];
    sum += x[(size_t)p3 * DIM + d];
  }
  for (; j < j1; ++j) sum += x[(size_t)perm[off + j] * DIM + d];
  partial[((size_t)k * SEG + s) * DIM + d] = sum;
}

__global__ void reduce_fb_kernel(const float* __restrict__ partial, const int* __restrict__ counts,
                                 float* __restrict__ c, float* __restrict__ c2) {
  __shared__ float wsum[4];
  int k = blockIdx.x, d = threadIdx.x;
  int cnt = counts[k];
  float s = 0.f;
#pragma unroll
  for (int t = 0; t < SEG; ++t) s += partial[((size_t)k * SEG + t) * DIM + d];
  float nc;
  if (cnt > 0)
    nc = s / fmaxf((float)cnt, 1.0f);
  else
    nc = c[(size_t)k * DIM + d];
  c[(size_t)k * DIM + d] = nc;
  float s2 = nc * nc;
#pragma unroll
  for (int m = 32; m >= 1; m >>= 1) s2 += __shfl_xor(s2, m, 64);
  if ((threadIdx.x & 63) == 0) wsum[threadIdx.x >> 6] = s2;
  __syncthreads();
  if (threadIdx.x == 0) c2[k] = wsum[0] + wsum[1] + wsum[2] + wsum[3];
}

__global__ void scan_fb_kernel(const int* __restrict__ hist, int* __restrict__ base,
                               int* __restrict__ counts, int* __restrict__ cbase) {
  __shared__ int h[128 * NK];
  int tid = threadIdx.x;
  for (int i = tid; i < 128 * NK; i += 256) h[i] = hist[i];
  __syncthreads();
  if (tid < NK) {
    int run = 0;
    for (int b = 0; b < 128; ++b) {
      int v = h[b * NK + tid];
      h[b * NK + tid] = run;
      run += v;
    }
    counts[tid] = run;
  }
  __syncthreads();
  if (tid == 0) {
    int cb = 0;
    for (int j = 0; j < NK; ++j) {
      cbase[j] = cb;
      cb += counts[j];
    }
  }
  __syncthreads();
  if (tid < NK) {
    int cbk = cbase[tid];
    for (int b = 0; b < 128; ++b) base[b * NK + tid] = h[b * NK + tid] + cbk;
  }
}

// ---------------------------------------------------------------------------
extern "C" void kernel_launch(void* const* d_in, const int* in_sizes, int n_in,
                              void* d_out, int out_size, void* d_ws, size_t ws_size,
                              hipStream_t stream) {
  const float* x = (const float*)d_in[0];
  char* ws = (char*)d_ws;

  const size_t NEED_BIG = 138283520;
  bool use_mfma = ws_size >= NEED_BIG;

  if (use_mfma) {
    _Float16* x1 = (_Float16*)(ws + 0);           // 64 MB
    _Float16* x2s = (_Float16*)(ws + 67108864);   // 64 MB
    float* c = (float*)(ws + 134217728);          // 128 KB (fp32 centroids)
    _Float16* ct = (_Float16*)(ws + 134348800);   // 128 KB (chunk-tiled split)
    float* c2 = (float*)(ws + 134479872);         // 512 B
    float* x2 = (float*)(ws + 134480384);         // 512 KB
    int* assignb = (int*)(ws + 135004672);        // 512 KB
    int* hist = (int*)(ws + 135528960);           // 64 KB
    int* base = (int*)(ws + 135594496);           // 64 KB
    int* counts = (int*)(ws + 135660032);         // 512 B
    int* cbase = (int*)(ws + 135660544);          // 512 B
    int* perm = (int*)(ws + 135661056);           // 512 KB
    float* partial = (float*)(ws + 136185344);    // 2 MB (>= MAXSEGS*DIM*4 = 1.18 MB)
    int* segbase = (int*)(ws + 138282496);        // 1 KB (129 ints)

    hipMemcpyAsync(c, x, (size_t)NK * DIM * sizeof(float), hipMemcpyDeviceToDevice, stream);
    hipMemsetAsync(hist, 0, 128 * NK * sizeof(int), stream);
    convert_x2_kernel<<<NPTS / 16, 256, 0, stream>>>(x, x1, x2s, x2);
    c2_kernel<<<NK, 64, 0, stream>>>(c, c2);
    convert_c_kernel<<<NK * DIM / 4 / 256, 256, 0, stream>>>(c, ct);

    for (int it = 0; it < NITER; ++it) {
      assign_mfma_kernel<true><<<NPTS / 128, 256, 0, stream>>>(x1, x2s, ct, x2, c2, assignb, hist);
      scan_kernel<<<1, 256, 0, stream>>>(hist, base, counts, cbase, segbase);
      scatter_kernel<<<NPTS / 1024, 64, 0, stream>>>(assignb, base, perm);
      seg_sum_v4_kernel<<<MAXSEGS, 256, 0, stream>>>(x1, x2s, perm, counts, cbase, segbase,
                                                     partial);
      reduce_kernel<<<NK, 256, 0, stream>>>(partial, counts, segbase, c, c2, ct);
    }
    assign_mfma_kernel<false><<<NPTS / 128, 256, 0, stream>>>(x1, x2s, ct, x2, c2, (int*)d_out,
                                                              hist);
  } else {
    float* c = (float*)(ws + 0);
    float* c2 = (float*)(ws + 131072);
    float* x2 = (float*)(ws + 132096);
    int* assignb = (int*)(ws + 656384);
    int* hist = (int*)(ws + 1180672);
    int* base = (int*)(ws + 1246208);
    int* counts = (int*)(ws + 1311744);
    int* cbase = (int*)(ws + 1312256);
    int* perm = (int*)(ws + 1312768);
    float* partial = (float*)(ws + 1837056);

    hipMemcpyAsync(c, x, (size_t)NK * DIM * sizeof(float), hipMemcpyDeviceToDevice, stream);
    x2_kernel<<<NPTS / 16, 256, 0, stream>>>(x, x2);
    c2_kernel<<<NK, 64, 0, stream>>>(c, c2);

    for (int it = 0; it < NITER; ++it) {
      assign_kernel<<<NPTS / 64, 256, 0, stream>>>(x, c, x2, c2, assignb);
      hist_kernel<<<NPTS / 1024, 256, 0, stream>>>(assignb, hist);
      scan_fb_kernel<<<1, 256, 0, stream>>>(hist, base, counts, cbase);
      scatter_kernel<<<NPTS / 1024, 64, 0, stream>>>(assignb, base, perm);
      seg_sum_kernel<<<dim3(NK, SEG), 256, 0, stream>>>(x, perm, counts, cbase, partial);
      reduce_fb_kernel<<<NK, 256, 0, stream>>>(partial, counts, c, c2);
    }
    assign_kernel<<<NPTS / 64, 256, 0, stream>>>(x, c, x2, c2, (int*)d_out);
  }
}